// Round 1
// baseline (222.157 us; speedup 1.0000x reference)
//
#include <hip/hip_runtime.h>

#define IN_N   4096
#define OW     4084          // (4096 + 2*1 - 15) + 1
#define KS     15
#define TILE_W 64
#define TILE_H 32
#define TILE_IC (TILE_W + KS - 1)   // 78
#define TILE_IR (TILE_H + KS - 1)   // 46
#define LDS_STRIDE 84               // 16B-aligned rows (84*4=336), bank shift 20/row

__global__ __launch_bounds__(256) void conv2d_direct(
    const float* __restrict__ x, const float* __restrict__ w,
    const float* __restrict__ bias, float* __restrict__ out)
{
    __shared__ float tile[TILE_IR * LDS_STRIDE];

    const int tid = threadIdx.x;
    const int bx = blockIdx.x, by = blockIdx.y;
    const int row0 = by * TILE_H - 1;   // pad = 1
    const int col0 = bx * TILE_W - 1;

    // ---- stage input tile (zero-fill outside [0,4096)^2) ----
    for (int i = tid; i < TILE_IR * TILE_IC; i += 256) {
        int tr = i / TILE_IC;
        int tc = i - tr * TILE_IC;
        int gr = row0 + tr, gc = col0 + tc;
        float v = 0.0f;
        if ((unsigned)gr < IN_N && (unsigned)gc < IN_N)
            v = x[gr * IN_N + gc];
        tile[tr * LDS_STRIDE + tc] = v;
    }
    __syncthreads();

    // ---- compute: each thread does 8 consecutive x-outputs ----
    const int tx = tid & 7;     // 8 threads in x  -> 64 outputs wide
    const int ty = tid >> 3;    // 32 threads in y
    float acc[8];
    #pragma unroll
    for (int j = 0; j < 8; ++j) acc[j] = 0.0f;

    const float* trow = &tile[ty * LDS_STRIDE + tx * 8];

    #pragma unroll 1
    for (int ky = 0; ky < KS; ++ky) {
        // 24-float sliding window (need 8+14=22), 16B-aligned ds_read_b128 x6
        float s[24];
        const float4* p = (const float4*)(trow + ky * LDS_STRIDE);
        #pragma unroll
        for (int q = 0; q < 6; ++q) {
            float4 t = p[q];
            s[4*q+0] = t.x; s[4*q+1] = t.y; s[4*q+2] = t.z; s[4*q+3] = t.w;
        }
        #pragma unroll
        for (int kx = 0; kx < KS; ++kx) {
            float wv = w[ky * KS + kx];   // uniform -> expect s_load
            #pragma unroll
            for (int j = 0; j < 8; ++j)
                acc[j] = fmaf(wv, s[kx + j], acc[j]);
        }
    }

    // ---- epilogue: bias + store ----
    float bv = bias[0];
    int oy  = by * TILE_H + ty;
    int ox0 = bx * TILE_W + tx * 8;
    if (oy < OW) {
        float* orow = &out[oy * OW + ox0];
        if (ox0 + 7 < OW) {
            float4 r0 = make_float4(acc[0]+bv, acc[1]+bv, acc[2]+bv, acc[3]+bv);
            float4 r1 = make_float4(acc[4]+bv, acc[5]+bv, acc[6]+bv, acc[7]+bv);
            float4* o = (float4*)orow;   // oy*4084*4 % 16 == 0, ox0*4 % 32 == 0
            o[0] = r0; o[1] = r1;
        } else {
            #pragma unroll
            for (int j = 0; j < 8; ++j) {
                int ox = ox0 + j;
                if (ox < OW) orow[j] = acc[j] + bv;
            }
        }
    }
}

extern "C" void kernel_launch(void* const* d_in, const int* in_sizes, int n_in,
                              void* d_out, int out_size, void* d_ws, size_t ws_size,
                              hipStream_t stream) {
    const float* x    = (const float*)d_in[0];
    const float* w    = (const float*)d_in[1];
    const float* bias = (const float*)d_in[2];
    float* out        = (float*)d_out;

    dim3 grid((OW + TILE_W - 1) / TILE_W,   // 64
              (OW + TILE_H - 1) / TILE_H);  // 128
    conv2d_direct<<<grid, dim3(256), 0, stream>>>(x, w, bias, out);
}

// Round 2
// 155.543 us; speedup vs baseline: 1.4283x; 1.4283x over previous
//
#include <hip/hip_runtime.h>
#include <hip/hip_bf16.h>

#define IN_N   4096
#define OW     4084          // (4096 + 2*1 - 15) + 1
#define KS     15
#define TILE   64            // 64x64 output tile per block (4 waves x 16 rows)
#define XROWS  78            // TILE + KS - 1
#define XCOLS  80            // staged cols: A k-window reaches t*16+31 -> 79
#define XS     88            // LDS row stride (halfwords); 88*2=176B, 11 mod 8 spreads groups

typedef __attribute__((ext_vector_type(8))) short v8s;   // 8 x bf16 (A/B frag)
typedef __attribute__((ext_vector_type(4))) float v4f;   // C/D frag

__device__ __forceinline__ unsigned short f2bf(float f) {
    union { float f; unsigned u; } c; c.f = f;
    unsigned r = c.u + 0x7fff + ((c.u >> 16) & 1);   // RTNE (inputs finite)
    return (unsigned short)(r >> 16);
}

__global__ __launch_bounds__(256) void conv2d_mfma(
    const float* __restrict__ x, const float* __restrict__ w,
    const float* __restrict__ bias, float* __restrict__ out)
{
    __shared__ unsigned short xtile[XROWS * XS] __attribute__((aligned(16)));
    __shared__ unsigned short Bbuf[KS * 512]   __attribute__((aligned(16)));  // 15 ky x 64 lanes x 8

    const int tid = threadIdx.x;
    const int X0 = blockIdx.x * TILE;
    const int Y0 = blockIdx.y * TILE;

    // ---- build banded B fragments (shared by all waves) ----
    // B_ky[k][n] = w[ky, k-n] if 0 <= k-n < 15 else 0
    // lane e holds B[k = (e>>4)*8 + j][n = e&15], j=0..7
    for (int p = tid; p < KS * 64; p += 256) {
        int ky = p >> 6, e = p & 63;
        int n = e & 15, quad = e >> 4;
        unsigned short vals[8];
        #pragma unroll
        for (int j = 0; j < 8; ++j) {
            int k = quad * 8 + j;
            int d = k - n;
            float wv = (d >= 0 && d < KS) ? w[ky * KS + d] : 0.0f;
            vals[j] = f2bf(wv);
        }
        *(v8s*)(&Bbuf[ky * 512 + e * 8]) = *(const v8s*)vals;
    }

    // ---- stage input tile fp32 -> bf16 (zero-fill OOB; covers pad=1) ----
    // LDS row 0 = global row Y0-1; LDS col 0 = global col X0-1
    for (int p = tid; p < XROWS * (XCOLS / 2); p += 256) {
        int tr = p / (XCOLS / 2);
        int cp = p - tr * (XCOLS / 2);
        int gr = Y0 - 1 + tr;
        int gc = X0 - 1 + cp * 2;
        float f0 = 0.0f, f1 = 0.0f;
        if ((unsigned)gr < (unsigned)IN_N) {
            const float* xr = x + (size_t)gr * IN_N;
            if ((unsigned)gc       < (unsigned)IN_N) f0 = xr[gc];
            if ((unsigned)(gc + 1) < (unsigned)IN_N) f1 = xr[gc + 1];
        }
        unsigned pack = (unsigned)f2bf(f0) | ((unsigned)f2bf(f1) << 16);
        *(unsigned*)(&xtile[tr * XS + cp * 2]) = pack;
    }
    __syncthreads();

    // ---- MFMA main loop: wave wv handles output rows Y0 + wv*16 .. +15 ----
    const int lane = tid & 63;
    const int wv   = tid >> 6;
    const int m    = lane & 15;
    const int quad = lane >> 4;

    v4f acc[4];
    #pragma unroll
    for (int t = 0; t < 4; ++t) acc[t] = (v4f){0.f, 0.f, 0.f, 0.f};

    const int rowbase = wv * 16 + m;        // + ky -> LDS row
    const int colbase = quad * 8;           // + t*16 -> LDS col (halfwords)

    #pragma unroll 5
    for (int ky = 0; ky < KS; ++ky) {
        v8s bfrag = *(const v8s*)(&Bbuf[ky * 512 + lane * 8]);
        const unsigned short* arow = &xtile[(rowbase + ky) * XS + colbase];
        #pragma unroll
        for (int t = 0; t < 4; ++t) {
            v8s afrag = *(const v8s*)(arow + t * 16);
            acc[t] = __builtin_amdgcn_mfma_f32_16x16x32_bf16(afrag, bfrag, acc[t], 0, 0, 0);
        }
    }

    // ---- epilogue: D[m,n] -> out; m = quad*4 + r, n = lane&15 ----
    const float bv = bias[0];
    const int orow0 = Y0 + wv * 16 + quad * 4;
    const int ocol0 = X0 + (lane & 15);
    #pragma unroll
    for (int t = 0; t < 4; ++t) {
        int oc = ocol0 + t * 16;
        if (oc < OW) {
            #pragma unroll
            for (int r = 0; r < 4; ++r) {
                int orow = orow0 + r;
                if (orow < OW)
                    out[(size_t)orow * OW + oc] = acc[t][r] + bv;
            }
        }
    }
}

extern "C" void kernel_launch(void* const* d_in, const int* in_sizes, int n_in,
                              void* d_out, int out_size, void* d_ws, size_t ws_size,
                              hipStream_t stream) {
    const float* x    = (const float*)d_in[0];
    const float* w    = (const float*)d_in[1];
    const float* bias = (const float*)d_in[2];
    float* out        = (float*)d_out;

    dim3 grid((OW + TILE - 1) / TILE, (OW + TILE - 1) / TILE);  // 64 x 64
    conv2d_mfma<<<grid, dim3(256), 0, stream>>>(x, w, bias, out);
}

// Round 3
// 136.437 us; speedup vs baseline: 1.6283x; 1.1400x over previous
//
#include <hip/hip_runtime.h>

#define IN_N   4096
#define OW     4084          // (4096 + 2*1 - 15) + 1
#define KS     15
#define TILE   64            // 64x64 output tile per block (4 waves x 16 rows)
#define XROWS  78            // TILE + KS - 1
#define XCOLS  80            // staged cols: A k-window reaches 48+24+7 = 79
#define XS     88            // LDS row stride (halfwords)
#define NBX    64            // grid x
#define NBY    64            // grid y

typedef __attribute__((ext_vector_type(8))) short v8s;   // 8 x bf16 (A/B frag)
typedef __attribute__((ext_vector_type(4))) float v4f;   // C/D frag

__device__ __forceinline__ unsigned short f2bf(float f) {
    union { float f; unsigned u; } c; c.f = f;
    unsigned r = c.u + 0x7fff + ((c.u >> 16) & 1);   // RTNE (inputs finite)
    return (unsigned short)(r >> 16);
}

// ---- pre-kernel: build the 15 banded-B MFMA fragments once into d_ws ----
// B_ky[k][n] = w[ky, k-n] if 0 <= k-n < 15 else 0
// lane e holds B[k = (e>>4)*8 + j][n = e&15], j = 0..7  (16 B per lane)
__global__ void build_B(const float* __restrict__ w, unsigned short* __restrict__ Bg) {
    int ky = blockIdx.x;         // 15
    int e  = threadIdx.x;        // 64
    int n = e & 15, quad = e >> 4;
    unsigned short vals[8];
    #pragma unroll
    for (int j = 0; j < 8; ++j) {
        int d = quad * 8 + j - n;
        vals[j] = (d >= 0 && d < KS) ? f2bf(w[ky * KS + d]) : (unsigned short)0;
    }
    *(v8s*)(&Bg[(ky * 64 + e) * 8]) = *(const v8s*)vals;
}

__global__ __launch_bounds__(256, 6) void conv2d_mfma2(
    const float* __restrict__ x, const unsigned short* __restrict__ Bg,
    const float* __restrict__ bias, float* __restrict__ out)
{
    __shared__ unsigned short xtile[XROWS * XS] __attribute__((aligned(16)));

    const int tid = threadIdx.x;
    const int bx = blockIdx.x, by = blockIdx.y;
    const int X0 = bx * TILE;
    const int Y0 = by * TILE;

    // ---- stage input tile fp32 -> bf16 ----
    // LDS (row, col) = global (Y0-1+row, X0-1+col), col in [0,80)
    const int tx = tid % 40;     // col-pair 0..39
    const int ty = tid / 40;     // 0..6 (ty==6 idle: 240 active threads)
    const bool interior = (bx > 0) & (bx < NBX - 1) & (by > 0) & (by < NBY - 1);

    if (ty < 6) {
        unsigned short* dst = &xtile[ty * XS + 2 * tx];   // 4B-aligned (XS even)
        if (interior) {
            const float* xr = x + (size_t)(Y0 - 1 + ty) * IN_N + (X0 - 1 + 2 * tx);
            #pragma unroll
            for (int i = 0; i < 13; ++i) {
                float f0 = xr[0], f1 = xr[1];
                *(unsigned*)dst = (unsigned)f2bf(f0) | ((unsigned)f2bf(f1) << 16);
                xr  += 6 * IN_N;
                dst += 6 * XS;
            }
        } else {
            const int gc0 = X0 - 1 + 2 * tx;
            #pragma unroll
            for (int i = 0; i < 13; ++i) {
                int gr = Y0 - 1 + ty + 6 * i;
                float f0 = 0.0f, f1 = 0.0f;
                if ((unsigned)gr < (unsigned)IN_N) {
                    const float* xr = x + (size_t)gr * IN_N;
                    if ((unsigned)gc0       < (unsigned)IN_N) f0 = xr[gc0];
                    if ((unsigned)(gc0 + 1) < (unsigned)IN_N) f1 = xr[gc0 + 1];
                }
                *(unsigned*)dst = (unsigned)f2bf(f0) | ((unsigned)f2bf(f1) << 16);
                dst += 6 * XS;
            }
        }
    }
    __syncthreads();

    // ---- MFMA main loop ----
    const int lane = tid & 63;
    const int wv   = tid >> 6;
    const int m    = lane & 15;
    const int quad = lane >> 4;

    v4f acc[4];
    #pragma unroll
    for (int t = 0; t < 4; ++t) acc[t] = (v4f){0.f, 0.f, 0.f, 0.f};

    const v8s* Bgv = (const v8s*)Bg;
    v8s bcur = Bgv[lane];                           // ky = 0 (L2-resident)
    const unsigned short* arow = &xtile[(wv * 16 + m) * XS + quad * 8];

    #pragma unroll
    for (int ky = 0; ky < KS; ++ky) {
        v8s bnext = (ky < KS - 1) ? Bgv[(ky + 1) * 64 + lane] : bcur;
        v8s a0 = *(const v8s*)(arow + 0);
        v8s a1 = *(const v8s*)(arow + 16);
        v8s a2 = *(const v8s*)(arow + 32);
        v8s a3 = *(const v8s*)(arow + 48);
        acc[0] = __builtin_amdgcn_mfma_f32_16x16x32_bf16(a0, bcur, acc[0], 0, 0, 0);
        acc[1] = __builtin_amdgcn_mfma_f32_16x16x32_bf16(a1, bcur, acc[1], 0, 0, 0);
        acc[2] = __builtin_amdgcn_mfma_f32_16x16x32_bf16(a2, bcur, acc[2], 0, 0, 0);
        acc[3] = __builtin_amdgcn_mfma_f32_16x16x32_bf16(a3, bcur, acc[3], 0, 0, 0);
        arow += XS;
        bcur = bnext;
    }

    // ---- epilogue: D[m,n] -> out; row = quad*4 + r, col = lane&15 (+t*16) ----
    const float bv = bias[0];
    const int orow0 = Y0 + wv * 16 + quad * 4;
    const int ocol0 = X0 + m;
    if (interior | ((bx < NBX - 1) & (by < NBY - 1))) {
        float* o0 = &out[(size_t)orow0 * OW + ocol0];
        #pragma unroll
        for (int t = 0; t < 4; ++t) {
            #pragma unroll
            for (int r = 0; r < 4; ++r)
                o0[(size_t)r * OW + t * 16] = acc[t][r] + bv;
        }
    } else {
        #pragma unroll
        for (int t = 0; t < 4; ++t) {
            int oc = ocol0 + t * 16;
            if (oc < OW) {
                #pragma unroll
                for (int r = 0; r < 4; ++r) {
                    int orow = orow0 + r;
                    if (orow < OW)
                        out[(size_t)orow * OW + oc] = acc[t][r] + bv;
                }
            }
        }
    }
}

extern "C" void kernel_launch(void* const* d_in, const int* in_sizes, int n_in,
                              void* d_out, int out_size, void* d_ws, size_t ws_size,
                              hipStream_t stream) {
    const float* x    = (const float*)d_in[0];
    const float* w    = (const float*)d_in[1];
    const float* bias = (const float*)d_in[2];
    float* out        = (float*)d_out;
    unsigned short* Bg = (unsigned short*)d_ws;     // 15 KiB of scratch

    build_B<<<dim3(KS), dim3(64), 0, stream>>>(w, Bg);
    dim3 grid(NBX, NBY);
    conv2d_mfma2<<<grid, dim3(256), 0, stream>>>(x, Bg, bias, out);
}